// Round 5
// baseline (302.016 us; speedup 1.0000x reference)
//
#include <hip/hip_runtime.h>
#include <math.h>
#include <stdint.h>

typedef __attribute__((ext_vector_type(8))) _Float16 f16x8;
typedef __attribute__((ext_vector_type(2))) __fp16 fp16x2;
typedef __attribute__((ext_vector_type(4))) float f32x4;
typedef __attribute__((ext_vector_type(16))) float f32x16;

static __device__ __forceinline__ unsigned short f2h(float f) {
  union { _Float16 h; unsigned short u; } v; v.h = (_Float16)f;
  return v.u;
}
static __device__ __forceinline__ float h2f(unsigned short u) {
  union { unsigned short u; _Float16 h; } v; v.u = u;
  return (float)v.h;
}
static __device__ __forceinline__ unsigned pkrtz(float a, float b) {
  union { fp16x2 h; unsigned u; } v;
  v.h = __builtin_amdgcn_cvt_pkrtz(a, b);
  return v.u;
}

#define GLOAD_LDS16(g, l) __builtin_amdgcn_global_load_lds( \
    (const __attribute__((address_space(1))) void*)(g),     \
    (__attribute__((address_space(3))) void*)(l), 16, 0, 0)

// ---------------- pack weights: W2 = [[Wr,-Wi],[Wi,Wr]] (1024x1024 f16), bias2 = br∓bi ----------------
__global__ __launch_bounds__(256) void pack_w(
    const float* __restrict__ Wr, const float* __restrict__ Wi,
    const float* __restrict__ br, const float* __restrict__ bi,
    unsigned short* __restrict__ W2, float* __restrict__ bias2) {
  int idx = blockIdx.x * 256 + threadIdx.x;
  int m = idx >> 10, k = idx & 1023;
  int o = m & 511, d = k & 511;
  float v;
  if (m < 512) v = (k < 512) ? Wr[o * 512 + d] : -Wi[o * 512 + d];
  else         v = (k < 512) ? Wi[o * 512 + d] :  Wr[o * 512 + d];
  W2[idx] = f2h(v);
  if (idx < 1024) {
    int oo = idx & 511;
    bias2[idx] = (idx < 512) ? (br[oo] - bi[oo]) : (br[oo] + bi[oo]);
  }
}

// ---------------- pack x: (B,D,2,S) f32 -> XT[(b*2048+s)][(c*512+d)] f16 (B^T layout) ----------------
__global__ __launch_bounds__(256) void pack_x(
    const float* __restrict__ x, unsigned short* __restrict__ XT) {
  __shared__ unsigned short tl[64][72];
  const int t = threadIdx.x;
  const int sBase = blockIdx.x * 64, dBase = blockIdx.y * 64;
  const int b = blockIdx.z >> 1, c = blockIdx.z & 1;
  const int r = t >> 2, cb = (t & 3) * 16;
  const float* src = x + (((size_t)(b * 512 + dBase + r) * 2 + c) * 2048 + sBase + cb);
#pragma unroll
  for (int j = 0; j < 16; j += 4) {
    float4 v = *(const float4*)(src + j);
    tl[cb + j + 0][r] = f2h(v.x);
    tl[cb + j + 1][r] = f2h(v.y);
    tl[cb + j + 2][r] = f2h(v.z);
    tl[cb + j + 3][r] = f2h(v.w);
  }
  __syncthreads();
  const int s = t >> 2, dc = (t & 3) * 16;
  unsigned short* dst = XT + ((size_t)(b * 2048 + sBase + s)) * 1024 + c * 512 + dBase + dc;
  *(uint4*)dst = *(const uint4*)&tl[s][dc];
  *(uint4*)(dst + 8) = *(const uint4*)&tl[s][dc + 8];
}

// ---------------- GEMM: C[1024][8192] = A(1024x1024) * Bt(8192x1024)^T, f16 in, fp32 acc ----------------
template <int MODE>
__global__ __launch_bounds__(256) void gemm_bt(
    const unsigned short* __restrict__ A, const unsigned short* __restrict__ Bt,
    const float* __restrict__ bias, unsigned short* __restrict__ Cb,
    float* __restrict__ Cf) {
  __shared__ unsigned short As[128 * 32];
  __shared__ unsigned short Bs[128 * 32];
  const int t = threadIdx.x;
  const int wave = t >> 6, lane = t & 63;
  const int wr = wave >> 1, wc = wave & 1;
  const int mBase = blockIdx.y * 128, nBase = blockIdx.x * 128;
  const int z = blockIdx.z;
  A += (size_t)z * 1024 * 1024;
  bias += z * 1024;
  if (MODE == 0) Cb += (size_t)z * 1024 * 8192;
  const int lr = lane & 15, lk = (lane >> 4) * 8;
  f32x4 acc[4][4] = {};
  const int grow = wave * 32 + (lane >> 2);
  const int gcol = (lane & 3) * 8;
  const unsigned short* ga = A + (size_t)(mBase + grow) * 1024 + gcol;
  const unsigned short* gb = Bt + (size_t)(nBase + grow) * 1024 + gcol;
  unsigned short* lA = &As[wave * 1024];
  unsigned short* lB = &Bs[wave * 1024];
  for (int k0 = 0; k0 < 1024; k0 += 32) {
    __syncthreads();
    GLOAD_LDS16(ga + k0, lA);
    GLOAD_LDS16(ga + 16 * 1024 + k0, lA + 512);
    GLOAD_LDS16(gb + k0, lB);
    GLOAD_LDS16(gb + 16 * 1024 + k0, lB + 512);
    __syncthreads();
    f16x8 af[4], bfr[4];
#pragma unroll
    for (int i = 0; i < 4; ++i) {
      af[i]  = *(const f16x8*)&As[(wr * 64 + i * 16 + lr) * 32 + lk];
      bfr[i] = *(const f16x8*)&Bs[(wc * 64 + i * 16 + lr) * 32 + lk];
    }
#pragma unroll
    for (int i = 0; i < 4; ++i)
#pragma unroll
      for (int j = 0; j < 4; ++j)
        acc[i][j] = __builtin_amdgcn_mfma_f32_16x16x32_f16(af[i], bfr[j], acc[i][j], 0, 0, 0);
  }
  const int cr = (lane >> 4) * 4, cc = lane & 15;
#pragma unroll
  for (int i = 0; i < 4; ++i) {
#pragma unroll
    for (int j = 0; j < 4; ++j) {
      const int m0 = mBase + wr * 64 + i * 16 + cr;
      const int n0 = nBase + wc * 64 + j * 16 + cc;
#pragma unroll
      for (int g = 0; g < 4; ++g) {
        float v = acc[i][j][g] + bias[m0 + g];
        if (MODE == 0) {
          Cb[(size_t)(m0 + g) * 8192 + n0] = f2h(v);
        } else {
          const int m = m0 + g;
          const int c = m >> 9, o = m & 511;
          const int b = n0 >> 11, s = n0 & 2047;
          Cf[(size_t)b * 2097152 + (size_t)o * 4096 + c * 2048 + s] = v;
        }
      }
    }
  }
}

// ---------------- magnitudes: Cq/Ck (channel-major f16) -> Qm/Km[(bh*2048+s)][64] f16 ----------------
__global__ __launch_bounds__(256) void mag_qk(
    const unsigned short* __restrict__ Cq, const unsigned short* __restrict__ Ck,
    unsigned short* __restrict__ Qm, unsigned short* __restrict__ Km) {
  __shared__ unsigned short tl[64][72];
  const unsigned short* C = blockIdx.z ? Ck : Cq;
  unsigned short* Out = blockIdx.z ? Km : Qm;
  const int t = threadIdx.x;
  const int sBase = blockIdx.x * 64;
  const int bh = blockIdx.y, b = bh >> 3, h = bh & 7;
  const int d = t >> 2, sc = (t & 3) * 16;
  const unsigned short* pr = C + (size_t)(h * 64 + d) * 8192 + b * 2048 + sBase + sc;
  const unsigned short* pi = pr + (size_t)512 * 8192;
  unsigned short rb[16], ib[16];
  *(uint4*)&rb[0] = *(const uint4*)pr;  *(uint4*)&rb[8] = *(const uint4*)(pr + 8);
  *(uint4*)&ib[0] = *(const uint4*)pi;  *(uint4*)&ib[8] = *(const uint4*)(pi + 8);
#pragma unroll
  for (int j = 0; j < 16; ++j) {
    float fr = h2f(rb[j]), fi = h2f(ib[j]);
    tl[sc + j][d] = f2h(sqrtf(fr * fr + fi * fi + 1e-8f));
  }
  __syncthreads();
  const int s = t >> 2, dc = (t & 3) * 16;
  unsigned short* dst = Out + ((size_t)bh * 2048 + sBase + s) * 64 + dc;
  *(uint4*)dst = *(const uint4*)&tl[s][dc];
  *(uint4*)(dst + 8) = *(const uint4*)&tl[s][dc + 8];
}

// ---------------- flash attention, LDS-free swapped 32x32 structure ----------------
// Per wave: 32 q-rows. QK^T swapped: mfma(A=K, B=Q) -> S col=lane&31=q, row(reg)=kv.
// Softmax fully lane-local; P -> PV A-frags via cvt_pkrtz + v_permlane32_swap_b32.
// K/V read straight from global (L1/L2 resident; no LDS, no barriers).
__global__ __launch_bounds__(256) void attn(
    const unsigned short* __restrict__ Qm, const unsigned short* __restrict__ Km,
    const unsigned short* __restrict__ Cv, unsigned short* __restrict__ OutT) {
  const int t = threadIdx.x, wave = t >> 6, lane = t & 63;
  // XCD-aware decode: same-bh blocks share an XCD's L2 (id%8 = XCD round-robin)
  const int id = blockIdx.x;
  const int xcd = id & 7, within = id >> 3;
  const int bh = xcd * 4 + (within >> 4);
  const int qtile = within & 15;
  const int b = bh >> 3, h = bh & 7;
  const int q31 = lane & 31, hi = lane >> 5;
  const int qBase = qtile * 128 + wave * 32;
  const float ls = 0.18033688f;  // log2(e)/sqrt(DK)

  // Q B-frags (col=q, k=d): 4 frags over DK=64
  f16x8 qf[4];
  {
    const unsigned short* qp = Qm + ((size_t)bh * 2048 + qBase + q31) * 64 + hi * 8;
    qf[0] = *(const f16x8*)qp;
    qf[1] = *(const f16x8*)(qp + 16);
    qf[2] = *(const f16x8*)(qp + 32);
    qf[3] = *(const f16x8*)(qp + 48);
  }
  f32x16 Or[2] = {}, Oi[2] = {};
  float m = -1e30f, l = 0.f;

  const unsigned short* kmB = Km + ((size_t)bh * 2048 + q31) * 64 + hi * 8;
  const unsigned short* vrB = Cv + ((size_t)(h * 64 + q31)) * 8192 + b * 2048 + hi * 8;
  const unsigned short* viB = vrB + (size_t)512 * 8192;

  for (int t0 = 0; t0 < 2048; t0 += 64) {
    // ---- QK^T (swapped): S[kb] = K x Q, col=q row=kv ----
    f32x16 S[2] = {};
#pragma unroll
    for (int kb = 0; kb < 2; ++kb) {
      const unsigned short* kp = kmB + (size_t)(t0 + kb * 32) * 64;
#pragma unroll
      for (int db = 0; db < 4; ++db) {
        f16x8 kf = *(const f16x8*)(kp + db * 16);
        S[kb] = __builtin_amdgcn_mfma_f32_32x32x16_f16(kf, qf[db], S[kb], 0, 0, 0);
      }
    }
    // ---- row max (lane-local + 1 cross-half shuffle) ----
    float m0a = fmaxf(S[0][0], S[0][1]), m0b = fmaxf(S[0][2], S[0][3]);
#pragma unroll
    for (int r = 4; r < 16; r += 4) {
      m0a = fmaxf(m0a, fmaxf(S[0][r], S[0][r + 1]));
      m0b = fmaxf(m0b, fmaxf(S[0][r + 2], S[0][r + 3]));
    }
#pragma unroll
    for (int r = 0; r < 16; r += 4) {
      m0a = fmaxf(m0a, fmaxf(S[1][r], S[1][r + 1]));
      m0b = fmaxf(m0b, fmaxf(S[1][r + 2], S[1][r + 3]));
    }
    float vmax = fmaxf(m0a, m0b);
    vmax = fmaxf(vmax, __shfl_xor(vmax, 32, 64));
    float pmax = vmax * ls;
    // ---- defer-max rescale (rare) ----
    if (__any(pmax > m + 8.0f)) {
      float mnew = fmaxf(m, pmax);
      float al = __builtin_amdgcn_exp2f(m - mnew);
      m = mnew;
      l *= al;
#pragma unroll
      for (int r = 0; r < 16; ++r) {
        const int qloc = (r & 3) + 8 * (r >> 2) + 4 * hi;
        float ao = __shfl(al, qloc, 64);
        Or[0][r] *= ao; Or[1][r] *= ao;
        Oi[0][r] *= ao; Oi[1][r] *= ao;
      }
    }
    // ---- p = exp2(S*ls - m), lane-local sum ----
    float p[2][16];
    float ps0 = 0.f, ps1 = 0.f;
#pragma unroll
    for (int kb = 0; kb < 2; ++kb)
#pragma unroll
      for (int r = 0; r < 16; r += 2) {
        float pa_ = __builtin_amdgcn_exp2f(fmaf(S[kb][r], ls, -m));
        float pb_ = __builtin_amdgcn_exp2f(fmaf(S[kb][r + 1], ls, -m));
        p[kb][r] = pa_; p[kb][r + 1] = pb_;
        ps0 += pa_; ps1 += pb_;
      }
    float ps = ps0 + ps1;
    ps += __shfl_xor(ps, 32, 64);
    l += ps;
    // ---- P -> PV A-frags: cvt_pkrtz + permlane32_swap (exchange across lane halves) ----
    f16x8 pa[4];
#pragma unroll
    for (int ks = 0; ks < 4; ++ks) {
      const float* pp = &p[ks >> 1][8 * (ks & 1)];
      unsigned c0 = pkrtz(pp[0], pp[1]);
      unsigned c1 = pkrtz(pp[2], pp[3]);
      unsigned d0 = pkrtz(pp[4], pp[5]);
      unsigned d1 = pkrtz(pp[6], pp[7]);
      asm volatile("v_permlane32_swap_b32 %0, %1" : "+v"(c0), "+v"(d0));
      asm volatile("v_permlane32_swap_b32 %0, %1" : "+v"(c1), "+v"(d1));
      union { unsigned u[4]; f16x8 v; } w;
      w.u[0] = c0; w.u[1] = c1; w.u[2] = d0; w.u[3] = d1;
      pa[ks] = w.v;
    }
    // ---- PV: O[j] += P x V (B col=d, k=kv), V straight from global ----
#pragma unroll
    for (int ks = 0; ks < 4; ++ks) {
      const size_t co = (size_t)(t0 + ks * 16);
#pragma unroll
      for (int j = 0; j < 2; ++j) {
        f16x8 vr = *(const f16x8*)(vrB + (size_t)j * 32 * 8192 + co);
        f16x8 vi = *(const f16x8*)(viB + (size_t)j * 32 * 8192 + co);
        Or[j] = __builtin_amdgcn_mfma_f32_32x32x16_f16(pa[ks], vr, Or[j], 0, 0, 0);
        Oi[j] = __builtin_amdgcn_mfma_f32_32x32x16_f16(pa[ks], vi, Oi[j], 0, 0, 0);
      }
    }
  }
  // ---- epilogue: divide by row-sum (redistribute to O layout), store ----
  float linv = 1.0f / l;
#pragma unroll
  for (int r = 0; r < 16; ++r) {
    const int qloc = (r & 3) + 8 * (r >> 2) + 4 * hi;
    float iv = __shfl(linv, qloc, 64);
    unsigned short* orow = OutT + ((size_t)b * 2048 + qBase + qloc) * 1024 + h * 64;
    orow[q31]       = f2h(Or[0][r] * iv);
    orow[32 + q31]  = f2h(Or[1][r] * iv);
    orow[512 + q31] = f2h(Oi[0][r] * iv);
    orow[544 + q31] = f2h(Oi[1][r] * iv);
  }
}

extern "C" void kernel_launch(void* const* d_in, const int* in_sizes, int n_in,
                              void* d_out, int out_size, void* d_ws, size_t ws_size,
                              hipStream_t stream) {
  (void)in_sizes; (void)n_in; (void)out_size; (void)ws_size;
  const float* x = (const float*)d_in[0];

  // workspace layout: XT 16.78M | W2 8.39M | bias2 16K | Cqkv 50.33M  => ~75.5 MB
  unsigned short* XT = (unsigned short*)d_ws;
  unsigned short* W2 = XT + (size_t)8192 * 1024;
  float* bias2 = (float*)(W2 + (size_t)4 * 1024 * 1024);
  unsigned short* Cqkv = (unsigned short*)(bias2 + 4096);
  // Qm/Km live in d_out (dead before final GEMM overwrites d_out)
  unsigned short* Qm = (unsigned short*)d_out;
  unsigned short* Km = Qm + (size_t)4 * 8 * 2048 * 64;
  // OutT reuses Cq slab (dead after mag_qk)
  unsigned short* OutT = Cqkv;

  for (int s = 0; s < 4; ++s) {
    pack_w<<<4096, 256, 0, stream>>>(
        (const float*)d_in[1 + 4 * s], (const float*)d_in[2 + 4 * s],
        (const float*)d_in[3 + 4 * s], (const float*)d_in[4 + 4 * s],
        W2 + (size_t)s * 1024 * 1024, bias2 + s * 1024);
  }
  pack_x<<<dim3(32, 8, 8), 256, 0, stream>>>(x, XT);
  gemm_bt<0><<<dim3(64, 8, 3), 256, 0, stream>>>(W2, XT, bias2, Cqkv, nullptr);
  mag_qk<<<dim3(32, 32, 2), 256, 0, stream>>>(Cqkv, Cqkv + (size_t)1024 * 8192, Qm, Km);
  attn<<<512, 256, 0, stream>>>(Qm, Km, Cqkv + (size_t)2 * 1024 * 8192, OutT);
  gemm_bt<1><<<dim3(64, 8, 1), 256, 0, stream>>>(
      W2 + (size_t)3 * 1024 * 1024, OutT, bias2 + 3 * 1024, nullptr, (float*)d_out);
}

// Round 7
// 296.866 us; speedup vs baseline: 1.0173x; 1.0173x over previous
//
#include <hip/hip_runtime.h>
#include <math.h>
#include <stdint.h>

typedef __attribute__((ext_vector_type(8))) _Float16 f16x8;
typedef __attribute__((ext_vector_type(2))) __fp16 fp16x2;
typedef __attribute__((ext_vector_type(4))) float f32x4;
typedef __attribute__((ext_vector_type(16))) float f32x16;

static __device__ __forceinline__ unsigned short f2h(float f) {
  union { _Float16 h; unsigned short u; } v; v.h = (_Float16)f;
  return v.u;
}
static __device__ __forceinline__ float h2f(unsigned short u) {
  union { unsigned short u; _Float16 h; } v; v.u = u;
  return (float)v.h;
}
static __device__ __forceinline__ unsigned pkrtz(float a, float b) {
  union { fp16x2 h; unsigned u; } v;
  v.h = __builtin_amdgcn_cvt_pkrtz(a, b);
  return v.u;
}

#define GLOAD_LDS16(g, l) __builtin_amdgcn_global_load_lds( \
    (const __attribute__((address_space(1))) void*)(g),     \
    (__attribute__((address_space(3))) void*)(l), 16, 0, 0)

// ---------------- pack weights: W2 = [[Wr,-Wi],[Wi,Wr]] (1024x1024 f16), bias2 = br∓bi ----------------
__global__ __launch_bounds__(256) void pack_w(
    const float* __restrict__ Wr, const float* __restrict__ Wi,
    const float* __restrict__ br, const float* __restrict__ bi,
    unsigned short* __restrict__ W2, float* __restrict__ bias2) {
  int idx = blockIdx.x * 256 + threadIdx.x;
  int m = idx >> 10, k = idx & 1023;
  int o = m & 511, d = k & 511;
  float v;
  if (m < 512) v = (k < 512) ? Wr[o * 512 + d] : -Wi[o * 512 + d];
  else         v = (k < 512) ? Wi[o * 512 + d] :  Wr[o * 512 + d];
  W2[idx] = f2h(v);
  if (idx < 1024) {
    int oo = idx & 511;
    bias2[idx] = (idx < 512) ? (br[oo] - bi[oo]) : (br[oo] + bi[oo]);
  }
}

// ---------------- pack x: (B,D,2,S) f32 -> XT[(b*2048+s)][(c*512+d)] f16 (B^T layout) ----------------
__global__ __launch_bounds__(256) void pack_x(
    const float* __restrict__ x, unsigned short* __restrict__ XT) {
  __shared__ unsigned short tl[64][72];
  const int t = threadIdx.x;
  const int sBase = blockIdx.x * 64, dBase = blockIdx.y * 64;
  const int b = blockIdx.z >> 1, c = blockIdx.z & 1;
  const int r = t >> 2, cb = (t & 3) * 16;
  const float* src = x + (((size_t)(b * 512 + dBase + r) * 2 + c) * 2048 + sBase + cb);
#pragma unroll
  for (int j = 0; j < 16; j += 4) {
    float4 v = *(const float4*)(src + j);
    tl[cb + j + 0][r] = f2h(v.x);
    tl[cb + j + 1][r] = f2h(v.y);
    tl[cb + j + 2][r] = f2h(v.z);
    tl[cb + j + 3][r] = f2h(v.w);
  }
  __syncthreads();
  const int s = t >> 2, dc = (t & 3) * 16;
  unsigned short* dst = XT + ((size_t)(b * 2048 + sBase + s)) * 1024 + c * 512 + dBase + dc;
  *(uint4*)dst = *(const uint4*)&tl[s][dc];
  *(uint4*)(dst + 8) = *(const uint4*)&tl[s][dc + 8];
}

// ---------------- GEMM: C[1024][8192] = A(1024x1024) * Bt(8192x1024)^T, f16 in, fp32 acc ----------------
template <int MODE>
__global__ __launch_bounds__(256) void gemm_bt(
    const unsigned short* __restrict__ A, const unsigned short* __restrict__ Bt,
    const float* __restrict__ bias, unsigned short* __restrict__ Cb,
    float* __restrict__ Cf) {
  __shared__ unsigned short As[128 * 32];
  __shared__ unsigned short Bs[128 * 32];
  const int t = threadIdx.x;
  const int wave = t >> 6, lane = t & 63;
  const int wr = wave >> 1, wc = wave & 1;
  const int mBase = blockIdx.y * 128, nBase = blockIdx.x * 128;
  const int z = blockIdx.z;
  A += (size_t)z * 1024 * 1024;
  bias += z * 1024;
  if (MODE == 0) Cb += (size_t)z * 1024 * 8192;
  const int lr = lane & 15, lk = (lane >> 4) * 8;
  f32x4 acc[4][4] = {};
  const int grow = wave * 32 + (lane >> 2);
  const int gcol = (lane & 3) * 8;
  const unsigned short* ga = A + (size_t)(mBase + grow) * 1024 + gcol;
  const unsigned short* gb = Bt + (size_t)(nBase + grow) * 1024 + gcol;
  unsigned short* lA = &As[wave * 1024];
  unsigned short* lB = &Bs[wave * 1024];
  for (int k0 = 0; k0 < 1024; k0 += 32) {
    __syncthreads();
    GLOAD_LDS16(ga + k0, lA);
    GLOAD_LDS16(ga + 16 * 1024 + k0, lA + 512);
    GLOAD_LDS16(gb + k0, lB);
    GLOAD_LDS16(gb + 16 * 1024 + k0, lB + 512);
    __syncthreads();
    f16x8 af[4], bfr[4];
#pragma unroll
    for (int i = 0; i < 4; ++i) {
      af[i]  = *(const f16x8*)&As[(wr * 64 + i * 16 + lr) * 32 + lk];
      bfr[i] = *(const f16x8*)&Bs[(wc * 64 + i * 16 + lr) * 32 + lk];
    }
#pragma unroll
    for (int i = 0; i < 4; ++i)
#pragma unroll
      for (int j = 0; j < 4; ++j)
        acc[i][j] = __builtin_amdgcn_mfma_f32_16x16x32_f16(af[i], bfr[j], acc[i][j], 0, 0, 0);
  }
  const int cr = (lane >> 4) * 4, cc = lane & 15;
#pragma unroll
  for (int i = 0; i < 4; ++i) {
#pragma unroll
    for (int j = 0; j < 4; ++j) {
      const int m0 = mBase + wr * 64 + i * 16 + cr;
      const int n0 = nBase + wc * 64 + j * 16 + cc;
#pragma unroll
      for (int g = 0; g < 4; ++g) {
        float v = acc[i][j][g] + bias[m0 + g];
        if (MODE == 0) {
          Cb[(size_t)(m0 + g) * 8192 + n0] = f2h(v);
        } else {
          const int m = m0 + g;
          const int c = m >> 9, o = m & 511;
          const int b = n0 >> 11, s = n0 & 2047;
          Cf[(size_t)b * 2097152 + (size_t)o * 4096 + c * 2048 + s] = v;
        }
      }
    }
  }
}

// ---------------- magnitudes: Cq/Ck (channel-major f16) -> Qm/Km[(bh*2048+s)][64] f16 ----------------
__global__ __launch_bounds__(256) void mag_qk(
    const unsigned short* __restrict__ Cq, const unsigned short* __restrict__ Ck,
    unsigned short* __restrict__ Qm, unsigned short* __restrict__ Km) {
  __shared__ unsigned short tl[64][72];
  const unsigned short* C = blockIdx.z ? Ck : Cq;
  unsigned short* Out = blockIdx.z ? Km : Qm;
  const int t = threadIdx.x;
  const int sBase = blockIdx.x * 64;
  const int bh = blockIdx.y, b = bh >> 3, h = bh & 7;
  const int d = t >> 2, sc = (t & 3) * 16;
  const unsigned short* pr = C + (size_t)(h * 64 + d) * 8192 + b * 2048 + sBase + sc;
  const unsigned short* pi = pr + (size_t)512 * 8192;
  unsigned short rb[16], ib[16];
  *(uint4*)&rb[0] = *(const uint4*)pr;  *(uint4*)&rb[8] = *(const uint4*)(pr + 8);
  *(uint4*)&ib[0] = *(const uint4*)pi;  *(uint4*)&ib[8] = *(const uint4*)(pi + 8);
#pragma unroll
  for (int j = 0; j < 16; ++j) {
    float fr = h2f(rb[j]), fi = h2f(ib[j]);
    tl[sc + j][d] = f2h(sqrtf(fr * fr + fi * fi + 1e-8f));
  }
  __syncthreads();
  const int s = t >> 2, dc = (t & 3) * 16;
  unsigned short* dst = Out + ((size_t)bh * 2048 + sBase + s) * 64 + dc;
  *(uint4*)dst = *(const uint4*)&tl[s][dc];
  *(uint4*)(dst + 8) = *(const uint4*)&tl[s][dc + 8];
}

// ---------------- flash attention, LDS-free swapped 32x32, staged-batch-load version ----------------
// Per wave: 32 q-rows. QK^T swapped: mfma(A=K, B=Q) -> S col=lane&31=q, row(reg)=kv.
// K loads batch ahead of QK; V loads batch right after QK (kf dead), before the
// softmax, so their latency hides under softmax VALU. No occupancy cap (avoid
// forced spilling around the permlane asm — R6 regression).
__global__ __launch_bounds__(256) void attn(
    const unsigned short* __restrict__ Qm, const unsigned short* __restrict__ Km,
    const unsigned short* __restrict__ Cv, unsigned short* __restrict__ OutT) {
  const int t = threadIdx.x, wave = t >> 6, lane = t & 63;
  // XCD-aware decode: same-bh blocks share an XCD's L2 (id%8 = XCD round-robin)
  const int id = blockIdx.x;
  const int xcd = id & 7, within = id >> 3;
  const int bh = xcd * 4 + (within >> 4);
  const int qtile = within & 15;
  const int b = bh >> 3, h = bh & 7;
  const int q31 = lane & 31, hi = lane >> 5;
  const int qBase = qtile * 128 + wave * 32;
  const float ls = 0.18033688f;  // log2(e)/sqrt(DK)

  // Q B-frags (col=q, k=d): 4 frags over DK=64
  f16x8 qf[4];
  {
    const unsigned short* qp = Qm + ((size_t)bh * 2048 + qBase + q31) * 64 + hi * 8;
    qf[0] = *(const f16x8*)qp;
    qf[1] = *(const f16x8*)(qp + 16);
    qf[2] = *(const f16x8*)(qp + 32);
    qf[3] = *(const f16x8*)(qp + 48);
  }
  f32x16 Or[2] = {}, Oi[2] = {};
  float m = -1e30f, l = 0.f;

  const unsigned short* kmB = Km + ((size_t)bh * 2048 + q31) * 64 + hi * 8;
  const unsigned short* vrB = Cv + ((size_t)(h * 64 + q31)) * 8192 + b * 2048 + hi * 8;
  const unsigned short* viB = vrB + (size_t)512 * 8192;

  for (int t0 = 0; t0 < 2048; t0 += 64) {
    // ---- batch K loads (8), then QK^T consuming them ----
    f16x8 kf[2][4];
#pragma unroll
    for (int kb = 0; kb < 2; ++kb) {
      const unsigned short* kp = kmB + (size_t)(t0 + kb * 32) * 64;
#pragma unroll
      for (int db = 0; db < 4; ++db)
        kf[kb][db] = *(const f16x8*)(kp + db * 16);
    }
    f32x16 S[2] = {};
#pragma unroll
    for (int kb = 0; kb < 2; ++kb)
#pragma unroll
      for (int db = 0; db < 4; ++db)
        S[kb] = __builtin_amdgcn_mfma_f32_32x32x16_f16(kf[kb][db], qf[db], S[kb], 0, 0, 0);
    // ---- batch V loads (16) now; latency hides under the softmax below ----
    f16x8 vr[4][2], vi[4][2];
#pragma unroll
    for (int ks = 0; ks < 4; ++ks) {
      const size_t co = (size_t)(t0 + ks * 16);
#pragma unroll
      for (int j = 0; j < 2; ++j) {
        vr[ks][j] = *(const f16x8*)(vrB + (size_t)j * 32 * 8192 + co);
        vi[ks][j] = *(const f16x8*)(viB + (size_t)j * 32 * 8192 + co);
      }
    }
    // ---- row max (lane-local + 1 cross-half shuffle) ----
    float m0a = fmaxf(S[0][0], S[0][1]), m0b = fmaxf(S[0][2], S[0][3]);
#pragma unroll
    for (int r = 4; r < 16; r += 4) {
      m0a = fmaxf(m0a, fmaxf(S[0][r], S[0][r + 1]));
      m0b = fmaxf(m0b, fmaxf(S[0][r + 2], S[0][r + 3]));
    }
#pragma unroll
    for (int r = 0; r < 16; r += 4) {
      m0a = fmaxf(m0a, fmaxf(S[1][r], S[1][r + 1]));
      m0b = fmaxf(m0b, fmaxf(S[1][r + 2], S[1][r + 3]));
    }
    float vmax = fmaxf(m0a, m0b);
    vmax = fmaxf(vmax, __shfl_xor(vmax, 32, 64));
    float pmax = vmax * ls;
    // ---- defer-max rescale (rare) ----
    if (__any(pmax > m + 8.0f)) {
      float mnew = fmaxf(m, pmax);
      float al = __builtin_amdgcn_exp2f(m - mnew);
      m = mnew;
      l *= al;
#pragma unroll
      for (int r = 0; r < 16; ++r) {
        const int qloc = (r & 3) + 8 * (r >> 2) + 4 * hi;
        float ao = __shfl(al, qloc, 64);
        Or[0][r] *= ao; Or[1][r] *= ao;
        Oi[0][r] *= ao; Oi[1][r] *= ao;
      }
    }
    // ---- p = exp2(S*ls - m), lane-local sum ----
    float p[2][16];
    float ps0 = 0.f, ps1 = 0.f;
#pragma unroll
    for (int kb = 0; kb < 2; ++kb)
#pragma unroll
      for (int r = 0; r < 16; r += 2) {
        float pa_ = __builtin_amdgcn_exp2f(fmaf(S[kb][r], ls, -m));
        float pb_ = __builtin_amdgcn_exp2f(fmaf(S[kb][r + 1], ls, -m));
        p[kb][r] = pa_; p[kb][r + 1] = pb_;
        ps0 += pa_; ps1 += pb_;
      }
    float ps = ps0 + ps1;
    ps += __shfl_xor(ps, 32, 64);
    l += ps;
    // ---- P -> PV A-frags: cvt_pkrtz + permlane32_swap (exchange across lane halves) ----
    f16x8 pa[4];
#pragma unroll
    for (int ks = 0; ks < 4; ++ks) {
      const float* pp = &p[ks >> 1][8 * (ks & 1)];
      unsigned c0 = pkrtz(pp[0], pp[1]);
      unsigned c1 = pkrtz(pp[2], pp[3]);
      unsigned d0 = pkrtz(pp[4], pp[5]);
      unsigned d1 = pkrtz(pp[6], pp[7]);
      asm volatile("v_permlane32_swap_b32 %0, %1" : "+v"(c0), "+v"(d0));
      asm volatile("v_permlane32_swap_b32 %0, %1" : "+v"(c1), "+v"(d1));
      union { unsigned u[4]; f16x8 v; } w;
      w.u[0] = c0; w.u[1] = c1; w.u[2] = d0; w.u[3] = d1;
      pa[ks] = w.v;
    }
    // ---- PV: O[j] += P x V (B col=d, k=kv), V already in registers ----
#pragma unroll
    for (int ks = 0; ks < 4; ++ks)
#pragma unroll
      for (int j = 0; j < 2; ++j) {
        Or[j] = __builtin_amdgcn_mfma_f32_32x32x16_f16(pa[ks], vr[ks][j], Or[j], 0, 0, 0);
        Oi[j] = __builtin_amdgcn_mfma_f32_32x32x16_f16(pa[ks], vi[ks][j], Oi[j], 0, 0, 0);
      }
  }
  // ---- epilogue: divide by row-sum (redistribute to O layout), store ----
  float linv = 1.0f / l;
#pragma unroll
  for (int r = 0; r < 16; ++r) {
    const int qloc = (r & 3) + 8 * (r >> 2) + 4 * hi;
    float iv = __shfl(linv, qloc, 64);
    unsigned short* orow = OutT + ((size_t)b * 2048 + qBase + qloc) * 1024 + h * 64;
    orow[q31]       = f2h(Or[0][r] * iv);
    orow[32 + q31]  = f2h(Or[1][r] * iv);
    orow[512 + q31] = f2h(Oi[0][r] * iv);
    orow[544 + q31] = f2h(Oi[1][r] * iv);
  }
}

extern "C" void kernel_launch(void* const* d_in, const int* in_sizes, int n_in,
                              void* d_out, int out_size, void* d_ws, size_t ws_size,
                              hipStream_t stream) {
  (void)in_sizes; (void)n_in; (void)out_size; (void)ws_size;
  const float* x = (const float*)d_in[0];

  // workspace layout: XT 16.78M | W2 8.39M | bias2 16K | Cqkv 50.33M  => ~75.5 MB
  unsigned short* XT = (unsigned short*)d_ws;
  unsigned short* W2 = XT + (size_t)8192 * 1024;
  float* bias2 = (float*)(W2 + (size_t)4 * 1024 * 1024);
  unsigned short* Cqkv = (unsigned short*)(bias2 + 4096);
  // Qm/Km live in d_out (dead before final GEMM overwrites d_out)
  unsigned short* Qm = (unsigned short*)d_out;
  unsigned short* Km = Qm + (size_t)4 * 8 * 2048 * 64;
  // OutT reuses Cq slab (dead after mag_qk)
  unsigned short* OutT = Cqkv;

  for (int s = 0; s < 4; ++s) {
    pack_w<<<4096, 256, 0, stream>>>(
        (const float*)d_in[1 + 4 * s], (const float*)d_in[2 + 4 * s],
        (const float*)d_in[3 + 4 * s], (const float*)d_in[4 + 4 * s],
        W2 + (size_t)s * 1024 * 1024, bias2 + s * 1024);
  }
  pack_x<<<dim3(32, 8, 8), 256, 0, stream>>>(x, XT);
  gemm_bt<0><<<dim3(64, 8, 3), 256, 0, stream>>>(W2, XT, bias2, Cqkv, nullptr);
  mag_qk<<<dim3(32, 32, 2), 256, 0, stream>>>(Cqkv, Cqkv + (size_t)1024 * 8192, Qm, Km);
  attn<<<512, 256, 0, stream>>>(Qm, Km, Cqkv + (size_t)2 * 1024 * 8192, OutT);
  gemm_bt<1><<<dim3(64, 8, 1), 256, 0, stream>>>(
      W2 + (size_t)3 * 1024 * 1024, OutT, bias2 + 3 * 1024, nullptr, (float*)d_out);
}

// Round 8
// 296.611 us; speedup vs baseline: 1.0182x; 1.0009x over previous
//
#include <hip/hip_runtime.h>
#include <math.h>
#include <stdint.h>

typedef __attribute__((ext_vector_type(8))) _Float16 f16x8;
typedef __attribute__((ext_vector_type(2))) __fp16 fp16x2;
typedef __attribute__((ext_vector_type(4))) float f32x4;
typedef __attribute__((ext_vector_type(16))) float f32x16;

static __device__ __forceinline__ unsigned short f2h(float f) {
  union { _Float16 h; unsigned short u; } v; v.h = (_Float16)f;
  return v.u;
}
static __device__ __forceinline__ float h2f(unsigned short u) {
  union { unsigned short u; _Float16 h; } v; v.u = u;
  return (float)v.h;
}
static __device__ __forceinline__ unsigned pkrtz(float a, float b) {
  union { fp16x2 h; unsigned u; } v;
  v.h = __builtin_amdgcn_cvt_pkrtz(a, b);
  return v.u;
}

#define GLOAD_LDS16(g, l) __builtin_amdgcn_global_load_lds( \
    (const __attribute__((address_space(1))) void*)(g),     \
    (__attribute__((address_space(3))) void*)(l), 16, 0, 0)

// ---------------- pack weights: W2 = [[Wr,-Wi],[Wi,Wr]] (1024x1024 f16), bias2 = br∓bi ----------------
__global__ __launch_bounds__(256) void pack_w(
    const float* __restrict__ Wr, const float* __restrict__ Wi,
    const float* __restrict__ br, const float* __restrict__ bi,
    unsigned short* __restrict__ W2, float* __restrict__ bias2) {
  int idx = blockIdx.x * 256 + threadIdx.x;
  int m = idx >> 10, k = idx & 1023;
  int o = m & 511, d = k & 511;
  float v;
  if (m < 512) v = (k < 512) ? Wr[o * 512 + d] : -Wi[o * 512 + d];
  else         v = (k < 512) ? Wi[o * 512 + d] :  Wr[o * 512 + d];
  W2[idx] = f2h(v);
  if (idx < 1024) {
    int oo = idx & 511;
    bias2[idx] = (idx < 512) ? (br[oo] - bi[oo]) : (br[oo] + bi[oo]);
  }
}

// ---------------- pack x: (B,D,2,S) f32 -> XT[(b*2048+s)][(c*512+d)] f16 (B^T layout) ----------------
__global__ __launch_bounds__(256) void pack_x(
    const float* __restrict__ x, unsigned short* __restrict__ XT) {
  __shared__ unsigned short tl[64][72];
  const int t = threadIdx.x;
  const int sBase = blockIdx.x * 64, dBase = blockIdx.y * 64;
  const int b = blockIdx.z >> 1, c = blockIdx.z & 1;
  const int r = t >> 2, cb = (t & 3) * 16;
  const float* src = x + (((size_t)(b * 512 + dBase + r) * 2 + c) * 2048 + sBase + cb);
#pragma unroll
  for (int j = 0; j < 16; j += 4) {
    float4 v = *(const float4*)(src + j);
    tl[cb + j + 0][r] = f2h(v.x);
    tl[cb + j + 1][r] = f2h(v.y);
    tl[cb + j + 2][r] = f2h(v.z);
    tl[cb + j + 3][r] = f2h(v.w);
  }
  __syncthreads();
  const int s = t >> 2, dc = (t & 3) * 16;
  unsigned short* dst = XT + ((size_t)(b * 2048 + sBase + s)) * 1024 + c * 512 + dBase + dc;
  *(uint4*)dst = *(const uint4*)&tl[s][dc];
  *(uint4*)(dst + 8) = *(const uint4*)&tl[s][dc + 8];
}

// ---------------- GEMM: C[1024][8192] = A(1024x1024) * Bt(8192x1024)^T, f16 in, fp32 acc ----------------
template <int MODE>
__global__ __launch_bounds__(256) void gemm_bt(
    const unsigned short* __restrict__ A, const unsigned short* __restrict__ Bt,
    const float* __restrict__ bias, unsigned short* __restrict__ Cb,
    float* __restrict__ Cf) {
  __shared__ unsigned short As[128 * 32];
  __shared__ unsigned short Bs[128 * 32];
  const int t = threadIdx.x;
  const int wave = t >> 6, lane = t & 63;
  const int wr = wave >> 1, wc = wave & 1;
  const int mBase = blockIdx.y * 128, nBase = blockIdx.x * 128;
  const int z = blockIdx.z;
  A += (size_t)z * 1024 * 1024;
  bias += z * 1024;
  if (MODE == 0) Cb += (size_t)z * 1024 * 8192;
  const int lr = lane & 15, lk = (lane >> 4) * 8;
  f32x4 acc[4][4] = {};
  const int grow = wave * 32 + (lane >> 2);
  const int gcol = (lane & 3) * 8;
  const unsigned short* ga = A + (size_t)(mBase + grow) * 1024 + gcol;
  const unsigned short* gb = Bt + (size_t)(nBase + grow) * 1024 + gcol;
  unsigned short* lA = &As[wave * 1024];
  unsigned short* lB = &Bs[wave * 1024];
  for (int k0 = 0; k0 < 1024; k0 += 32) {
    __syncthreads();
    GLOAD_LDS16(ga + k0, lA);
    GLOAD_LDS16(ga + 16 * 1024 + k0, lA + 512);
    GLOAD_LDS16(gb + k0, lB);
    GLOAD_LDS16(gb + 16 * 1024 + k0, lB + 512);
    __syncthreads();
    f16x8 af[4], bfr[4];
#pragma unroll
    for (int i = 0; i < 4; ++i) {
      af[i]  = *(const f16x8*)&As[(wr * 64 + i * 16 + lr) * 32 + lk];
      bfr[i] = *(const f16x8*)&Bs[(wc * 64 + i * 16 + lr) * 32 + lk];
    }
#pragma unroll
    for (int i = 0; i < 4; ++i)
#pragma unroll
      for (int j = 0; j < 4; ++j)
        acc[i][j] = __builtin_amdgcn_mfma_f32_16x16x32_f16(af[i], bfr[j], acc[i][j], 0, 0, 0);
  }
  const int cr = (lane >> 4) * 4, cc = lane & 15;
#pragma unroll
  for (int i = 0; i < 4; ++i) {
#pragma unroll
    for (int j = 0; j < 4; ++j) {
      const int m0 = mBase + wr * 64 + i * 16 + cr;
      const int n0 = nBase + wc * 64 + j * 16 + cc;
#pragma unroll
      for (int g = 0; g < 4; ++g) {
        float v = acc[i][j][g] + bias[m0 + g];
        if (MODE == 0) {
          Cb[(size_t)(m0 + g) * 8192 + n0] = f2h(v);
        } else {
          const int m = m0 + g;
          const int c = m >> 9, o = m & 511;
          const int b = n0 >> 11, s = n0 & 2047;
          Cf[(size_t)b * 2097152 + (size_t)o * 4096 + c * 2048 + s] = v;
        }
      }
    }
  }
}

// ---------------- magnitudes: Cq/Ck (channel-major f16) -> Qm/Km[(bh*2048+s)][64] f16 ----------------
__global__ __launch_bounds__(256) void mag_qk(
    const unsigned short* __restrict__ Cq, const unsigned short* __restrict__ Ck,
    unsigned short* __restrict__ Qm, unsigned short* __restrict__ Km) {
  __shared__ unsigned short tl[64][72];
  const unsigned short* C = blockIdx.z ? Ck : Cq;
  unsigned short* Out = blockIdx.z ? Km : Qm;
  const int t = threadIdx.x;
  const int sBase = blockIdx.x * 64;
  const int bh = blockIdx.y, b = bh >> 3, h = bh & 7;
  const int d = t >> 2, sc = (t & 3) * 16;
  const unsigned short* pr = C + (size_t)(h * 64 + d) * 8192 + b * 2048 + sBase + sc;
  const unsigned short* pi = pr + (size_t)512 * 8192;
  unsigned short rb[16], ib[16];
  *(uint4*)&rb[0] = *(const uint4*)pr;  *(uint4*)&rb[8] = *(const uint4*)(pr + 8);
  *(uint4*)&ib[0] = *(const uint4*)pi;  *(uint4*)&ib[8] = *(const uint4*)(pi + 8);
#pragma unroll
  for (int j = 0; j < 16; ++j) {
    float fr = h2f(rb[j]), fi = h2f(ib[j]);
    tl[sc + j][d] = f2h(sqrtf(fr * fr + fi * fi + 1e-8f));
  }
  __syncthreads();
  const int s = t >> 2, dc = (t & 3) * 16;
  unsigned short* dst = Out + ((size_t)bh * 2048 + sBase + s) * 64 + dc;
  *(uint4*)dst = *(const uint4*)&tl[s][dc];
  *(uint4*)(dst + 8) = *(const uint4*)&tl[s][dc + 8];
}

// ---------------- flash attention, LDS-free swapped 32x32, sched_barrier-pinned loads ----------------
// Per wave: 32 q-rows. QK^T swapped: mfma(A=K, B=Q) -> S col=lane&31=q, row(reg)=kv.
// K batch (8 loads) + sched_barrier(0); QK. V batch (16 loads) + sched_barrier(0);
// softmax VALU covers V latency; PV consumes in-register V. No occupancy cap.
__global__ __launch_bounds__(256) void attn(
    const unsigned short* __restrict__ Qm, const unsigned short* __restrict__ Km,
    const unsigned short* __restrict__ Cv, unsigned short* __restrict__ OutT) {
  const int t = threadIdx.x, wave = t >> 6, lane = t & 63;
  // XCD-aware decode: same-bh blocks share an XCD's L2 (id%8 = XCD round-robin)
  const int id = blockIdx.x;
  const int xcd = id & 7, within = id >> 3;
  const int bh = xcd * 4 + (within >> 4);
  const int qtile = within & 15;
  const int b = bh >> 3, h = bh & 7;
  const int q31 = lane & 31, hi = lane >> 5;
  const int qBase = qtile * 128 + wave * 32;
  const float ls = 0.18033688f;  // log2(e)/sqrt(DK)

  // Q B-frags (col=q, k=d): 4 frags over DK=64
  f16x8 qf[4];
  {
    const unsigned short* qp = Qm + ((size_t)bh * 2048 + qBase + q31) * 64 + hi * 8;
    qf[0] = *(const f16x8*)qp;
    qf[1] = *(const f16x8*)(qp + 16);
    qf[2] = *(const f16x8*)(qp + 32);
    qf[3] = *(const f16x8*)(qp + 48);
  }
  f32x16 Or[2] = {}, Oi[2] = {};
  float m = -1e30f, l = 0.f;

  const unsigned short* kmB = Km + ((size_t)bh * 2048 + q31) * 64 + hi * 8;
  const unsigned short* vrB = Cv + ((size_t)(h * 64 + q31)) * 8192 + b * 2048 + hi * 8;
  const unsigned short* viB = vrB + (size_t)512 * 8192;

  for (int t0 = 0; t0 < 2048; t0 += 64) {
    // ---- batch K loads (8); fence so the scheduler can't sink them ----
    f16x8 kf[2][4];
#pragma unroll
    for (int kb = 0; kb < 2; ++kb) {
      const unsigned short* kp = kmB + (size_t)(t0 + kb * 32) * 64;
#pragma unroll
      for (int db = 0; db < 4; ++db)
        kf[kb][db] = *(const f16x8*)(kp + db * 16);
    }
    __builtin_amdgcn_sched_barrier(0);
    // ---- QK^T (swapped): S[kb] = K x Q, col=q row=kv ----
    f32x16 S[2] = {};
#pragma unroll
    for (int kb = 0; kb < 2; ++kb)
#pragma unroll
      for (int db = 0; db < 4; ++db)
        S[kb] = __builtin_amdgcn_mfma_f32_32x32x16_f16(kf[kb][db], qf[db], S[kb], 0, 0, 0);
    // ---- batch V loads (16); fence; latency hides under softmax below ----
    f16x8 vr[4][2], vi[4][2];
#pragma unroll
    for (int ks = 0; ks < 4; ++ks) {
      const size_t co = (size_t)(t0 + ks * 16);
#pragma unroll
      for (int j = 0; j < 2; ++j) {
        vr[ks][j] = *(const f16x8*)(vrB + (size_t)j * 32 * 8192 + co);
        vi[ks][j] = *(const f16x8*)(viB + (size_t)j * 32 * 8192 + co);
      }
    }
    __builtin_amdgcn_sched_barrier(0);
    // ---- row max (lane-local + 1 cross-half shuffle) ----
    float m0a = fmaxf(S[0][0], S[0][1]), m0b = fmaxf(S[0][2], S[0][3]);
#pragma unroll
    for (int r = 4; r < 16; r += 4) {
      m0a = fmaxf(m0a, fmaxf(S[0][r], S[0][r + 1]));
      m0b = fmaxf(m0b, fmaxf(S[0][r + 2], S[0][r + 3]));
    }
#pragma unroll
    for (int r = 0; r < 16; r += 4) {
      m0a = fmaxf(m0a, fmaxf(S[1][r], S[1][r + 1]));
      m0b = fmaxf(m0b, fmaxf(S[1][r + 2], S[1][r + 3]));
    }
    float vmax = fmaxf(m0a, m0b);
    vmax = fmaxf(vmax, __shfl_xor(vmax, 32, 64));
    float pmax = vmax * ls;
    // ---- defer-max rescale (rare) ----
    if (__any(pmax > m + 8.0f)) {
      float mnew = fmaxf(m, pmax);
      float al = __builtin_amdgcn_exp2f(m - mnew);
      m = mnew;
      l *= al;
#pragma unroll
      for (int r = 0; r < 16; ++r) {
        const int qloc = (r & 3) + 8 * (r >> 2) + 4 * hi;
        float ao = __shfl(al, qloc, 64);
        Or[0][r] *= ao; Or[1][r] *= ao;
        Oi[0][r] *= ao; Oi[1][r] *= ao;
      }
    }
    // ---- p = exp2(S*ls - m), lane-local sum ----
    float p[2][16];
    float ps0 = 0.f, ps1 = 0.f;
#pragma unroll
    for (int kb = 0; kb < 2; ++kb)
#pragma unroll
      for (int r = 0; r < 16; r += 2) {
        float pa_ = __builtin_amdgcn_exp2f(fmaf(S[kb][r], ls, -m));
        float pb_ = __builtin_amdgcn_exp2f(fmaf(S[kb][r + 1], ls, -m));
        p[kb][r] = pa_; p[kb][r + 1] = pb_;
        ps0 += pa_; ps1 += pb_;
      }
    float ps = ps0 + ps1;
    ps += __shfl_xor(ps, 32, 64);
    l += ps;
    // ---- P -> PV A-frags: cvt_pkrtz + permlane32_swap (exchange across lane halves) ----
    f16x8 pa[4];
#pragma unroll
    for (int ks = 0; ks < 4; ++ks) {
      const float* pp = &p[ks >> 1][8 * (ks & 1)];
      unsigned c0 = pkrtz(pp[0], pp[1]);
      unsigned c1 = pkrtz(pp[2], pp[3]);
      unsigned d0 = pkrtz(pp[4], pp[5]);
      unsigned d1 = pkrtz(pp[6], pp[7]);
      asm volatile("v_permlane32_swap_b32 %0, %1" : "+v"(c0), "+v"(d0));
      asm volatile("v_permlane32_swap_b32 %0, %1" : "+v"(c1), "+v"(d1));
      union { unsigned u[4]; f16x8 v; } w;
      w.u[0] = c0; w.u[1] = c1; w.u[2] = d0; w.u[3] = d1;
      pa[ks] = w.v;
    }
    // ---- PV: O[j] += P x V (B col=d, k=kv), V already in registers ----
#pragma unroll
    for (int ks = 0; ks < 4; ++ks)
#pragma unroll
      for (int j = 0; j < 2; ++j) {
        Or[j] = __builtin_amdgcn_mfma_f32_32x32x16_f16(pa[ks], vr[ks][j], Or[j], 0, 0, 0);
        Oi[j] = __builtin_amdgcn_mfma_f32_32x32x16_f16(pa[ks], vi[ks][j], Oi[j], 0, 0, 0);
      }
  }
  // ---- epilogue: divide by row-sum (redistribute to O layout), store ----
  float linv = 1.0f / l;
#pragma unroll
  for (int r = 0; r < 16; ++r) {
    const int qloc = (r & 3) + 8 * (r >> 2) + 4 * hi;
    float iv = __shfl(linv, qloc, 64);
    unsigned short* orow = OutT + ((size_t)b * 2048 + qBase + qloc) * 1024 + h * 64;
    orow[q31]       = f2h(Or[0][r] * iv);
    orow[32 + q31]  = f2h(Or[1][r] * iv);
    orow[512 + q31] = f2h(Oi[0][r] * iv);
    orow[544 + q31] = f2h(Oi[1][r] * iv);
  }
}

extern "C" void kernel_launch(void* const* d_in, const int* in_sizes, int n_in,
                              void* d_out, int out_size, void* d_ws, size_t ws_size,
                              hipStream_t stream) {
  (void)in_sizes; (void)n_in; (void)out_size; (void)ws_size;
  const float* x = (const float*)d_in[0];

  // workspace layout: XT 16.78M | W2 8.39M | bias2 16K | Cqkv 50.33M  => ~75.5 MB
  unsigned short* XT = (unsigned short*)d_ws;
  unsigned short* W2 = XT + (size_t)8192 * 1024;
  float* bias2 = (float*)(W2 + (size_t)4 * 1024 * 1024);
  unsigned short* Cqkv = (unsigned short*)(bias2 + 4096);
  // Qm/Km live in d_out (dead before final GEMM overwrites d_out)
  unsigned short* Qm = (unsigned short*)d_out;
  unsigned short* Km = Qm + (size_t)4 * 8 * 2048 * 64;
  // OutT reuses Cq slab (dead after mag_qk)
  unsigned short* OutT = Cqkv;

  for (int s = 0; s < 4; ++s) {
    pack_w<<<4096, 256, 0, stream>>>(
        (const float*)d_in[1 + 4 * s], (const float*)d_in[2 + 4 * s],
        (const float*)d_in[3 + 4 * s], (const float*)d_in[4 + 4 * s],
        W2 + (size_t)s * 1024 * 1024, bias2 + s * 1024);
  }
  pack_x<<<dim3(32, 8, 8), 256, 0, stream>>>(x, XT);
  gemm_bt<0><<<dim3(64, 8, 3), 256, 0, stream>>>(W2, XT, bias2, Cqkv, nullptr);
  mag_qk<<<dim3(32, 32, 2), 256, 0, stream>>>(Cqkv, Cqkv + (size_t)1024 * 8192, Qm, Km);
  attn<<<512, 256, 0, stream>>>(Qm, Km, Cqkv + (size_t)2 * 1024 * 8192, OutT);
  gemm_bt<1><<<dim3(64, 8, 1), 256, 0, stream>>>(
      W2 + (size_t)3 * 1024 * 1024, OutT, bias2 + 3 * 1024, nullptr, (float*)d_out);
}

// Round 9
// 209.745 us; speedup vs baseline: 1.4399x; 1.4141x over previous
//
#include <hip/hip_runtime.h>
#include <math.h>
#include <stdint.h>

typedef __attribute__((ext_vector_type(8))) _Float16 f16x8;
typedef __attribute__((ext_vector_type(2))) __fp16 fp16x2;
typedef __attribute__((ext_vector_type(4))) float f32x4;
typedef __attribute__((ext_vector_type(16))) float f32x16;

static __device__ __forceinline__ unsigned short f2h(float f) {
  union { _Float16 h; unsigned short u; } v; v.h = (_Float16)f;
  return v.u;
}
static __device__ __forceinline__ float h2f(unsigned short u) {
  union { unsigned short u; _Float16 h; } v; v.u = u;
  return (float)v.h;
}
static __device__ __forceinline__ unsigned pkrtz(float a, float b) {
  union { fp16x2 h; unsigned u; } v;
  v.h = __builtin_amdgcn_cvt_pkrtz(a, b);
  return v.u;
}

#define GLOAD_LDS16(g, l) __builtin_amdgcn_global_load_lds( \
    (const __attribute__((address_space(1))) void*)(g),     \
    (__attribute__((address_space(3))) void*)(l), 16, 0, 0)

// ---------------- pack weights: W2 = [[Wr,-Wi],[Wi,Wr]] (1024x1024 f16), bias2 = br∓bi ----------------
__global__ __launch_bounds__(256) void pack_w(
    const float* __restrict__ Wr, const float* __restrict__ Wi,
    const float* __restrict__ br, const float* __restrict__ bi,
    unsigned short* __restrict__ W2, float* __restrict__ bias2) {
  int idx = blockIdx.x * 256 + threadIdx.x;
  int m = idx >> 10, k = idx & 1023;
  int o = m & 511, d = k & 511;
  float v;
  if (m < 512) v = (k < 512) ? Wr[o * 512 + d] : -Wi[o * 512 + d];
  else         v = (k < 512) ? Wi[o * 512 + d] :  Wr[o * 512 + d];
  W2[idx] = f2h(v);
  if (idx < 1024) {
    int oo = idx & 511;
    bias2[idx] = (idx < 512) ? (br[oo] - bi[oo]) : (br[oo] + bi[oo]);
  }
}

// ---------------- pack x: (B,D,2,S) f32 -> XT[(b*2048+s)][(c*512+d)] f16 (B^T layout) ----------------
__global__ __launch_bounds__(256) void pack_x(
    const float* __restrict__ x, unsigned short* __restrict__ XT) {
  __shared__ unsigned short tl[64][72];
  const int t = threadIdx.x;
  const int sBase = blockIdx.x * 64, dBase = blockIdx.y * 64;
  const int b = blockIdx.z >> 1, c = blockIdx.z & 1;
  const int r = t >> 2, cb = (t & 3) * 16;
  const float* src = x + (((size_t)(b * 512 + dBase + r) * 2 + c) * 2048 + sBase + cb);
#pragma unroll
  for (int j = 0; j < 16; j += 4) {
    float4 v = *(const float4*)(src + j);
    tl[cb + j + 0][r] = f2h(v.x);
    tl[cb + j + 1][r] = f2h(v.y);
    tl[cb + j + 2][r] = f2h(v.z);
    tl[cb + j + 3][r] = f2h(v.w);
  }
  __syncthreads();
  const int s = t >> 2, dc = (t & 3) * 16;
  unsigned short* dst = XT + ((size_t)(b * 2048 + sBase + s)) * 1024 + c * 512 + dBase + dc;
  *(uint4*)dst = *(const uint4*)&tl[s][dc];
  *(uint4*)(dst + 8) = *(const uint4*)&tl[s][dc + 8];
}

// ---------------- GEMM: C[1024][8192] = A(1024x1024) * Bt(8192x1024)^T, f16 in, fp32 acc ----------------
// MODE 0: z=0,1 (Q,K): f16 channel-major; z=2 (V): fragment-major V_f for attn.
// MODE 1: fp32 scattered into d_out (B,D,2,S).
template <int MODE>
__global__ __launch_bounds__(256) void gemm_bt(
    const unsigned short* __restrict__ A, const unsigned short* __restrict__ Bt,
    const float* __restrict__ bias, unsigned short* __restrict__ Cb,
    float* __restrict__ Cf) {
  __shared__ unsigned short As[128 * 32];
  __shared__ unsigned short Bs[128 * 32];
  const int t = threadIdx.x;
  const int wave = t >> 6, lane = t & 63;
  const int wr = wave >> 1, wc = wave & 1;
  const int mBase = blockIdx.y * 128, nBase = blockIdx.x * 128;
  const int z = blockIdx.z;
  A += (size_t)z * 1024 * 1024;
  bias += z * 1024;
  if (MODE == 0) Cb += (size_t)z * 1024 * 8192;
  const int lr = lane & 15, lk = (lane >> 4) * 8;
  f32x4 acc[4][4] = {};
  const int grow = wave * 32 + (lane >> 2);
  const int gcol = (lane & 3) * 8;
  const unsigned short* ga = A + (size_t)(mBase + grow) * 1024 + gcol;
  const unsigned short* gb = Bt + (size_t)(nBase + grow) * 1024 + gcol;
  unsigned short* lA = &As[wave * 1024];
  unsigned short* lB = &Bs[wave * 1024];
  for (int k0 = 0; k0 < 1024; k0 += 32) {
    __syncthreads();
    GLOAD_LDS16(ga + k0, lA);
    GLOAD_LDS16(ga + 16 * 1024 + k0, lA + 512);
    GLOAD_LDS16(gb + k0, lB);
    GLOAD_LDS16(gb + 16 * 1024 + k0, lB + 512);
    __syncthreads();
    f16x8 af[4], bfr[4];
#pragma unroll
    for (int i = 0; i < 4; ++i) {
      af[i]  = *(const f16x8*)&As[(wr * 64 + i * 16 + lr) * 32 + lk];
      bfr[i] = *(const f16x8*)&Bs[(wc * 64 + i * 16 + lr) * 32 + lk];
    }
#pragma unroll
    for (int i = 0; i < 4; ++i)
#pragma unroll
      for (int j = 0; j < 4; ++j)
        acc[i][j] = __builtin_amdgcn_mfma_f32_16x16x32_f16(af[i], bfr[j], acc[i][j], 0, 0, 0);
  }
  const int cr = (lane >> 4) * 4, cc = lane & 15;
#pragma unroll
  for (int i = 0; i < 4; ++i) {
#pragma unroll
    for (int j = 0; j < 4; ++j) {
      const int m0 = mBase + wr * 64 + i * 16 + cr;
      const int n0 = nBase + wc * 64 + j * 16 + cc;
#pragma unroll
      for (int g = 0; g < 4; ++g) {
        float v = acc[i][j][g] + bias[m0 + g];
        if (MODE == 0) {
          const int m = m0 + g;
          if (z == 2) {
            // V fragment-major: [bh][tile32][ks4][j2][ri2][lane64][8]
            const int ri = m >> 9, mm = m & 511;
            const int h = mm >> 6, dloc = mm & 63;
            const int jj = dloc >> 5, q31 = dloc & 31;
            const int b = n0 >> 11, s = n0 & 2047;
            const int tile = s >> 6, ks = (s >> 4) & 3, hi = (s >> 3) & 1, e = s & 7;
            const size_t flat =
                ((((((size_t)(b * 8 + h) * 32 + tile) * 4 + ks) * 2 + jj) * 2 + ri) * 64 +
                 hi * 32 + q31) * 8 + e;
            Cb[flat] = f2h(v);
          } else {
            Cb[(size_t)m * 8192 + n0] = f2h(v);
          }
        } else {
          const int m = m0 + g;
          const int c = m >> 9, o = m & 511;
          const int b = n0 >> 11, s = n0 & 2047;
          Cf[(size_t)b * 2097152 + (size_t)o * 4096 + c * 2048 + s] = v;
        }
      }
    }
  }
}

// ---------------- magnitudes: Qm row-major [(bh*2048+s)][64]; Km FRAGMENT-major ----------------
// Km_f: [bh][tile32][kb2][db4][lane64][8] so attn's kf loads are lane-contiguous 1KB.
__global__ __launch_bounds__(256) void mag_qk(
    const unsigned short* __restrict__ Cq, const unsigned short* __restrict__ Ck,
    unsigned short* __restrict__ Qm, unsigned short* __restrict__ Km) {
  __shared__ unsigned short tl[64][72];
  const int isK = blockIdx.z;
  const unsigned short* C = isK ? Ck : Cq;
  unsigned short* Out = isK ? Km : Qm;
  const int t = threadIdx.x;
  const int sBase = blockIdx.x * 64;
  const int bh = blockIdx.y, b = bh >> 3, h = bh & 7;
  const int d = t >> 2, sc = (t & 3) * 16;
  const unsigned short* pr = C + (size_t)(h * 64 + d) * 8192 + b * 2048 + sBase + sc;
  const unsigned short* pi = pr + (size_t)512 * 8192;
  unsigned short rb[16], ib[16];
  *(uint4*)&rb[0] = *(const uint4*)pr;  *(uint4*)&rb[8] = *(const uint4*)(pr + 8);
  *(uint4*)&ib[0] = *(const uint4*)pi;  *(uint4*)&ib[8] = *(const uint4*)(pi + 8);
#pragma unroll
  for (int j = 0; j < 16; ++j) {
    float fr = h2f(rb[j]), fi = h2f(ib[j]);
    tl[sc + j][d] = f2h(sqrtf(fr * fr + fi * fi + 1e-8f));
  }
  __syncthreads();
  const int s = t >> 2, dc = (t & 3) * 16;
  if (isK) {
    const int kb = s >> 5, q31 = s & 31, db = dc >> 4;
    unsigned short* dstf = Out +
        ((((size_t)bh * 32 + blockIdx.x) * 2 + kb) * 4 + db) * 512 + (size_t)q31 * 8;
    *(uint4*)dstf = *(const uint4*)&tl[s][dc];          // hi = 0
    *(uint4*)(dstf + 256) = *(const uint4*)&tl[s][dc + 8];  // hi = 1
  } else {
    unsigned short* dst = Out + ((size_t)bh * 2048 + sBase + s) * 64 + dc;
    *(uint4*)dst = *(const uint4*)&tl[s][dc];
    *(uint4*)(dst + 8) = *(const uint4*)&tl[s][dc + 8];
  }
}

// ---------------- flash attention, LDS-free swapped 32x32, fragment-major K/V (coalesced) ----------------
// Per wave: 32 q-rows. QK^T swapped: mfma(A=K, B=Q) -> S col=lane&31=q, row(reg)=kv.
// K/V loads are base + const + lane*16B: 64 lanes = 1KB contiguous per instruction.
__global__ __launch_bounds__(256) void attn(
    const unsigned short* __restrict__ Qm, const unsigned short* __restrict__ Km,
    const unsigned short* __restrict__ Vf, unsigned short* __restrict__ OutT) {
  const int t = threadIdx.x, wave = t >> 6, lane = t & 63;
  // XCD-aware decode: same-bh blocks share an XCD's L2 (id%8 = XCD round-robin)
  const int id = blockIdx.x;
  const int xcd = id & 7, within = id >> 3;
  const int bh = xcd * 4 + (within >> 4);
  const int qtile = within & 15;
  const int b = bh >> 3, h = bh & 7;
  const int q31 = lane & 31, hi = lane >> 5;
  const int qBase = qtile * 128 + wave * 32;
  const float ls = 0.18033688f;  // log2(e)/sqrt(DK)

  // Q B-frags (col=q, k=d): 4 frags over DK=64
  f16x8 qf[4];
  {
    const unsigned short* qp = Qm + ((size_t)bh * 2048 + qBase + q31) * 64 + hi * 8;
    qf[0] = *(const f16x8*)qp;
    qf[1] = *(const f16x8*)(qp + 16);
    qf[2] = *(const f16x8*)(qp + 32);
    qf[3] = *(const f16x8*)(qp + 48);
  }
  f32x16 Or[2] = {}, Oi[2] = {};
  float m = -1e30f, l = 0.f;

  // fragment-major bases (lane-contiguous)
  const unsigned short* kmF = Km + (size_t)bh * 131072 + (size_t)lane * 8;
  const unsigned short* vF  = Vf + (size_t)bh * 262144 + (size_t)lane * 8;

  for (int t0 = 0; t0 < 2048; t0 += 64) {
    const int tile = t0 >> 6;
    // ---- batch K loads (8 x 1KB coalesced) ----
    f16x8 kf[2][4];
#pragma unroll
    for (int kb = 0; kb < 2; ++kb)
#pragma unroll
      for (int db = 0; db < 4; ++db)
        kf[kb][db] = *(const f16x8*)(kmF + (size_t)(((tile * 2 + kb) * 4 + db)) * 512);
    __builtin_amdgcn_sched_barrier(0);
    // ---- QK^T (swapped): S[kb] = K x Q, col=q row=kv ----
    f32x16 S[2] = {};
#pragma unroll
    for (int kb = 0; kb < 2; ++kb)
#pragma unroll
      for (int db = 0; db < 4; ++db)
        S[kb] = __builtin_amdgcn_mfma_f32_32x32x16_f16(kf[kb][db], qf[db], S[kb], 0, 0, 0);
    // ---- batch V loads (16 x 1KB coalesced); latency hides under softmax ----
    f16x8 vr[4][2], vi[4][2];
#pragma unroll
    for (int ks = 0; ks < 4; ++ks)
#pragma unroll
      for (int j = 0; j < 2; ++j) {
        const size_t u = (size_t)(((tile * 4 + ks) * 2 + j) * 2) * 512;
        vr[ks][j] = *(const f16x8*)(vF + u);
        vi[ks][j] = *(const f16x8*)(vF + u + 512);
      }
    __builtin_amdgcn_sched_barrier(0);
    // ---- row max (lane-local + 1 cross-half shuffle) ----
    float m0a = fmaxf(S[0][0], S[0][1]), m0b = fmaxf(S[0][2], S[0][3]);
#pragma unroll
    for (int r = 4; r < 16; r += 4) {
      m0a = fmaxf(m0a, fmaxf(S[0][r], S[0][r + 1]));
      m0b = fmaxf(m0b, fmaxf(S[0][r + 2], S[0][r + 3]));
    }
#pragma unroll
    for (int r = 0; r < 16; r += 4) {
      m0a = fmaxf(m0a, fmaxf(S[1][r], S[1][r + 1]));
      m0b = fmaxf(m0b, fmaxf(S[1][r + 2], S[1][r + 3]));
    }
    float vmax = fmaxf(m0a, m0b);
    vmax = fmaxf(vmax, __shfl_xor(vmax, 32, 64));
    float pmax = vmax * ls;
    // ---- defer-max rescale (rare) ----
    if (__any(pmax > m + 8.0f)) {
      float mnew = fmaxf(m, pmax);
      float al = __builtin_amdgcn_exp2f(m - mnew);
      m = mnew;
      l *= al;
#pragma unroll
      for (int r = 0; r < 16; ++r) {
        const int qloc = (r & 3) + 8 * (r >> 2) + 4 * hi;
        float ao = __shfl(al, qloc, 64);
        Or[0][r] *= ao; Or[1][r] *= ao;
        Oi[0][r] *= ao; Oi[1][r] *= ao;
      }
    }
    // ---- p = exp2(S*ls - m), lane-local sum ----
    float p[2][16];
    float ps0 = 0.f, ps1 = 0.f;
#pragma unroll
    for (int kb = 0; kb < 2; ++kb)
#pragma unroll
      for (int r = 0; r < 16; r += 2) {
        float pa_ = __builtin_amdgcn_exp2f(fmaf(S[kb][r], ls, -m));
        float pb_ = __builtin_amdgcn_exp2f(fmaf(S[kb][r + 1], ls, -m));
        p[kb][r] = pa_; p[kb][r + 1] = pb_;
        ps0 += pa_; ps1 += pb_;
      }
    float ps = ps0 + ps1;
    ps += __shfl_xor(ps, 32, 64);
    l += ps;
    // ---- P -> PV A-frags: cvt_pkrtz + permlane32_swap (exchange across lane halves) ----
    f16x8 pa[4];
#pragma unroll
    for (int ks = 0; ks < 4; ++ks) {
      const float* pp = &p[ks >> 1][8 * (ks & 1)];
      unsigned c0 = pkrtz(pp[0], pp[1]);
      unsigned c1 = pkrtz(pp[2], pp[3]);
      unsigned d0 = pkrtz(pp[4], pp[5]);
      unsigned d1 = pkrtz(pp[6], pp[7]);
      asm volatile("v_permlane32_swap_b32 %0, %1" : "+v"(c0), "+v"(d0));
      asm volatile("v_permlane32_swap_b32 %0, %1" : "+v"(c1), "+v"(d1));
      union { unsigned u[4]; f16x8 v; } w;
      w.u[0] = c0; w.u[1] = c1; w.u[2] = d0; w.u[3] = d1;
      pa[ks] = w.v;
    }
    // ---- PV: O[j] += P x V (B col=d, k=kv), V already in registers ----
#pragma unroll
    for (int ks = 0; ks < 4; ++ks)
#pragma unroll
      for (int j = 0; j < 2; ++j) {
        Or[j] = __builtin_amdgcn_mfma_f32_32x32x16_f16(pa[ks], vr[ks][j], Or[j], 0, 0, 0);
        Oi[j] = __builtin_amdgcn_mfma_f32_32x32x16_f16(pa[ks], vi[ks][j], Oi[j], 0, 0, 0);
      }
  }
  // ---- epilogue: divide by row-sum (redistribute to O layout), store ----
  float linv = 1.0f / l;
#pragma unroll
  for (int r = 0; r < 16; ++r) {
    const int qloc = (r & 3) + 8 * (r >> 2) + 4 * hi;
    float iv = __shfl(linv, qloc, 64);
    unsigned short* orow = OutT + ((size_t)b * 2048 + qBase + qloc) * 1024 + h * 64;
    orow[q31]       = f2h(Or[0][r] * iv);
    orow[32 + q31]  = f2h(Or[1][r] * iv);
    orow[512 + q31] = f2h(Oi[0][r] * iv);
    orow[544 + q31] = f2h(Oi[1][r] * iv);
  }
}

extern "C" void kernel_launch(void* const* d_in, const int* in_sizes, int n_in,
                              void* d_out, int out_size, void* d_ws, size_t ws_size,
                              hipStream_t stream) {
  (void)in_sizes; (void)n_in; (void)out_size; (void)ws_size;
  const float* x = (const float*)d_in[0];

  // workspace layout: XT 16.78M | W2 8.39M | bias2 16K | Cqkv 50.33M  => ~75.5 MB
  unsigned short* XT = (unsigned short*)d_ws;
  unsigned short* W2 = XT + (size_t)8192 * 1024;
  float* bias2 = (float*)(W2 + (size_t)4 * 1024 * 1024);
  unsigned short* Cqkv = (unsigned short*)(bias2 + 4096);
  // Qm/Km live in d_out (dead before final GEMM overwrites d_out)
  unsigned short* Qm = (unsigned short*)d_out;
  unsigned short* Km = Qm + (size_t)4 * 8 * 2048 * 64;   // Km_f fragment-major, same size
  // V_f lives in the z=2 slab of Cqkv; OutT reuses Cq slab (dead after mag_qk)
  unsigned short* Vf = Cqkv + (size_t)2 * 1024 * 8192;
  unsigned short* OutT = Cqkv;

  for (int s = 0; s < 4; ++s) {
    pack_w<<<4096, 256, 0, stream>>>(
        (const float*)d_in[1 + 4 * s], (const float*)d_in[2 + 4 * s],
        (const float*)d_in[3 + 4 * s], (const float*)d_in[4 + 4 * s],
        W2 + (size_t)s * 1024 * 1024, bias2 + s * 1024);
  }
  pack_x<<<dim3(32, 8, 8), 256, 0, stream>>>(x, XT);
  gemm_bt<0><<<dim3(64, 8, 3), 256, 0, stream>>>(W2, XT, bias2, Cqkv, nullptr);
  mag_qk<<<dim3(32, 32, 2), 256, 0, stream>>>(Cqkv, Cqkv + (size_t)1024 * 8192, Qm, Km);
  attn<<<512, 256, 0, stream>>>(Qm, Km, Vf, OutT);
  gemm_bt<1><<<dim3(64, 8, 1), 256, 0, stream>>>(
      W2 + (size_t)3 * 1024 * 1024, OutT, bias2 + 3 * 1024, nullptr, (float*)d_out);
}